// Round 7
// baseline (491.891 us; speedup 1.0000x reference)
//
#include <hip/hip_runtime.h>
#include <hip/hip_bf16.h>

typedef __hip_bfloat16 bf16;
typedef __attribute__((ext_vector_type(8))) short s8v;
typedef __attribute__((ext_vector_type(4))) float f4v;
typedef __attribute__((ext_vector_type(2))) float f2v;
typedef unsigned short u16;
typedef unsigned int u32;
typedef unsigned char u8;
typedef long long i64;

#define NN 32768
#define NE 524288
#define D 128
#define H 4
#define C 32
#define R 5
#define BS 8192
#define NB 2048   // NE/256 partition blocks

__device__ __forceinline__ u16 f2bs(float x) { bf16 h = __float2bfloat16(x); return *(u16*)&h; }
__device__ __forceinline__ float bflo(u32 u) { return __uint_as_float(u << 16); }
__device__ __forceinline__ float bfhi(u32 u) { return __uint_as_float(u & 0xffff0000u); }
// fast bf16 pair pack: round-half-up (+0x8000) then byte-perm; 3 VALU instrs
__device__ __forceinline__ u32 pack2r(float a, float b) {
    u32 ua = __float_as_uint(a) + 0x8000u;
    u32 ub = __float_as_uint(b) + 0x8000u;
    return __builtin_amdgcn_perm(ub, ua, 0x07060302u);   // lo16=hi(a), hi16=hi(b)
}
__device__ __forceinline__ u16 rnd16(float a) {
    return (u16)((__float_as_uint(a) + 0x8000u) >> 16);
}
__device__ __forceinline__ float gelu_f(float x) {   // exact (value-path epilogue use)
    return 0.5f * x * (1.f + erff(x * 0.7071067811865475f));
}
// polynomial gelu on a packed f32 pair (logit path only):
// erf(t/sqrt2) ~ t*poly(t^2), t=clamp(x,-4,4); max |err| ~6.6e-3 near |x|~2.5.
__device__ __forceinline__ f2v gelu_pk(f2v x) {
    f2v t;
    t.x = fminf(fmaxf(x.x, -4.f), 4.f);   // v_med3_f32
    t.y = fminf(fmaxf(x.y, -4.f), 4.f);
    f2v s = t * t;
    f2v h = __builtin_elementwise_fma(s, (f2v)1.53421e-5f, (f2v)-7.13918e-4f);
    h = __builtin_elementwise_fma(s, h, (f2v)0.0129194f);
    h = __builtin_elementwise_fma(s, h, (f2v)-0.1207967f);
    h = __builtin_elementwise_fma(s, h, (f2v)0.794118f);
    f2v e = t * h;                         // ~erf(x/sqrt2)
    f2v hx = x * 0.5f;
    return __builtin_elementwise_fma(hx, e, hx);   // 0.5x + 0.5x*erf
}
// DPP rotate-add reduction across the 16 lanes of a DPP row (lanes 16q..16q+15).
template <int CTRL>
__device__ __forceinline__ float dpp_add(float v) {
    int t = __builtin_amdgcn_update_dpp(0, __float_as_int(v), CTRL, 0xf, 0xf, true);
    return v + __int_as_float(t);
}
__device__ __forceinline__ float rsum16(float v) {
    v = dpp_add<0x128>(v);   // row_ror:8
    v = dpp_add<0x124>(v);   // row_ror:4
    v = dpp_add<0x122>(v);   // row_ror:2
    v = dpp_add<0x121>(v);   // row_ror:1
    return v;
}

// ---- static device scratch ----
__device__ u16      g_x[NN * D];          // bf16 working activations
__device__ float    g_araw[NE * H];       // exp(logit), CSR-position indexed
__device__ u8       g_P8[R * NN * D];     // fp8 e4m3: x @ Rtop[r]   (logit path)
__device__ u8       g_Q8[R * NN * D];     // fp8 e4m3: x @ Rbot[r]   (logit path)
__device__ u16      g_xl[NN * D];         // bf16: x @ Wl + bl       (value path)
__device__ u8       g_xl8[NN * D];        // fp8 copy of xl          (logit path)
__device__ u16      g_WnF[26 * 2048 * 8]; // bf16 weights, MFMA B-frag order
__device__ int      g_cnt[NN];            // CSR: in-degree counts
__device__ int      g_cur[NN];            // CSR: scatter cursors
__device__ int      g_off[NN + 1];        // CSR: row offsets (by dst)
__device__ int      g_se[NE];             // CSR-ordered src node ids
__device__ int      g_de[NE];             // CSR-ordered dst node ids
__device__ int      g_re[NE];             // CSR-ordered relation ids
// relation-stable-partitioned edge list (R7): bucket by re, dst-order kept
__device__ int      g_bh[R * NB];         // per-block bucket counts -> offsets
__device__ int      g_hse[NE];            // re-partitioned src ids
__device__ int      g_hde[NE];            // re-partitioned dst ids
__device__ u32      g_hpr[NE];            // (re<<24) | csr_pos

__global__ void k_cvt(const float* __restrict__ e) {
    int i = blockIdx.x * 256 + threadIdx.x;   // NN*D/2 threads
    float2 v = *(const float2*)&e[(size_t)i * 2];
    ((u32*)g_x)[i] = pack2r(v.x, v.y);
}

// ---- CSR build (edge list identical for both layers: build once) ----
__global__ void k_zcnt() {
    int i = blockIdx.x * 256 + threadIdx.x;   // NN threads
    g_cnt[i] = 0; g_cur[i] = 0;
}
__global__ void k_count(const int* __restrict__ ei) {
    int i = blockIdx.x * 256 + threadIdx.x;   // NE threads
    atomicAdd(&g_cnt[ei[NE + i]], 1);
}
__global__ void k_scan() {   // 1 block, 1024 threads, 32 elems each
    __shared__ int sums[1024];
    const int t = threadIdx.x;
    const int base = t * 32;
    int local[32];
    int s = 0;
#pragma unroll
    for (int i = 0; i < 32; ++i) { local[i] = s; s += g_cnt[base + i]; }
    sums[t] = s;
    __syncthreads();
    for (int off = 1; off < 1024; off <<= 1) {
        int v = (t >= off) ? sums[t - off] : 0;
        __syncthreads();
        sums[t] += v;
        __syncthreads();
    }
    int chunkoff = (t == 0) ? 0 : sums[t - 1];
#pragma unroll
    for (int i = 0; i < 32; ++i) g_off[base + i] = chunkoff + local[i];
    if (t == 1023) g_off[NN] = sums[1023];
}
__global__ void k_scatter(const int* __restrict__ ei, const int* __restrict__ et) {
    int i = blockIdx.x * 256 + threadIdx.x;   // NE threads
    int d = ei[NE + i];
    int pos = g_off[d] + atomicAdd(&g_cur[d], 1);
    g_se[pos] = ei[i];
    g_de[pos] = d;
    g_re[pos] = et[i];
}

// ---- stable partition of the CSR edge list by relation (R7) ----
// Keeps dst-sorted order within each re bucket, so k_edge's dst-side gathers
// (Q8, xl8[de]) keep their locality while src-side gathers (P8[re][se]) are
// confined to one 4.2MB P8 slab at a time (25MB -> 8.4MB random working set).
__global__ void k_phist() {   // NB blocks x 256
    __shared__ int h[R];
    const int t = threadIdx.x, b = blockIdx.x;
    if (t < R) h[t] = 0;
    __syncthreads();
    atomicAdd(&h[g_re[b * 256 + t]], 1);
    __syncthreads();
    if (t < R) g_bh[t * NB + b] = h[t];
}
__global__ void k_pscan() {   // 1 block, 1024 threads, 10 elems each (R*NB=10240)
    __shared__ int sums[1024];
    const int t = threadIdx.x;
    const int base = t * 10;
    int local[10];
    int s = 0;
#pragma unroll
    for (int i = 0; i < 10; ++i) { local[i] = s; s += g_bh[base + i]; }
    sums[t] = s;
    __syncthreads();
    for (int off = 1; off < 1024; off <<= 1) {
        int v = (t >= off) ? sums[t - off] : 0;
        __syncthreads();
        sums[t] += v;
        __syncthreads();
    }
    int chunkoff = (t == 0) ? 0 : sums[t - 1];
#pragma unroll
    for (int i = 0; i < 10; ++i) g_bh[base + i] = chunkoff + local[i];   // exclusive
}
__global__ void k_pscat() {   // NB blocks x 256, stable within block via rank loop
    __shared__ u8 lre[256];
    __shared__ int bofs[R];
    const int t = threadIdx.x, b = blockIdx.x;
    const int i = b * 256 + t;
    const int re = g_re[i];
    lre[t] = (u8)re;
    if (t < R) bofs[t] = g_bh[t * NB + b];
    __syncthreads();
    int rank = 0;
    for (int j = 0; j < t; ++j) rank += (lre[j] == (u8)re);
    const int pos = bofs[re] + rank;
    g_hse[pos] = g_se[i];
    g_hde[pos] = g_de[i];
    g_hpr[pos] = ((u32)re << 24) | (u32)i;
}

// ---- weights -> bf16 MFMA B-fragment order (one layer, 13 matrices) ----
__global__ void k_prep(const float* __restrict__ Wl, const float* __restrict__ Rm,
                       const float* __restrict__ We, const float* __restrict__ Ow,
                       int base) {
    int f = blockIdx.x * 256 + threadIdx.x;   // frag id 0..2047
    int y = blockIdx.y;
    const float* src;
    if (y == 0) src = Wl;
    else if (y <= R) src = Rm + (size_t)(y - 1) * 2 * D * D;
    else if (y <= 2 * R) src = Rm + (size_t)(y - 1 - R) * 2 * D * D + D * D;
    else if (y == 11) src = We;
    else src = Ow;
    int lane = f & 63, nt = (f >> 6) & 7, s = f >> 9;
    int n = nt * 16 + (lane & 15);
    int ks = s * 32 + (lane >> 4) * 8;
    u16 tmp[8];
#pragma unroll
    for (int j = 0; j < 8; ++j) tmp[j] = f2bs(src[(size_t)(ks + j) * D + n]);
    *(uint4*)&g_WnF[((size_t)(base + y) * 2048 + f) * 8] = *(uint4*)tmp;
}

// ---- node transforms (MFMA, LDS-free): xl (bf16+fp8) / P[r],Q[r] (fp8) ----
// fused wsel groups: blockIdx.y in {0..3} covers wsel {0-2,3-5,6-8,9-10};
// A-fragments loaded once per group (r6, kept).
__global__ __launch_bounds__(256) void k_node(const float* __restrict__ bl, int wbase) {
    const int tid = threadIdx.x;
    const int n0 = blockIdx.x * 64;
    const int wstart = blockIdx.y * 3;              // 0,3,6,9
    const int wend = (wstart + 3 < 11) ? wstart + 3 : 11;
    const int l = tid & 63, w = tid >> 6;
    const int mrow = l & 15, quad = l >> 4;
    const u16* xrow = g_x + (size_t)(n0 + w * 16 + mrow) * D;

    s8v a[4];
#pragma unroll
    for (int s = 0; s < 4; ++s) a[s] = *(const s8v*)&xrow[s * 32 + quad * 8];

    for (int wsel = wstart; wsel < wend; ++wsel) {
        const u16* BF = g_WnF + (size_t)(wbase + wsel) * 2048 * 8;
        f4v acc[8];
#pragma unroll
        for (int nt = 0; nt < 8; ++nt) acc[nt] = (f4v){0.f, 0.f, 0.f, 0.f};
#pragma unroll
        for (int s = 0; s < 4; ++s) {
#pragma unroll
            for (int nt = 0; nt < 8; ++nt) {
                s8v b = *(const s8v*)&BF[(size_t)((s * 8 + nt) * 64 + l) * 8];
                acc[nt] = __builtin_amdgcn_mfma_f32_16x16x32_bf16(a[s], b, acc[nt], 0, 0, 0);
            }
        }

        if (wsel == 0) {
#pragma unroll
            for (int nt = 0; nt < 8; ++nt) {
                int col = nt * 16 + mrow;
                float bias = bl[col];
                float v[4];
#pragma unroll
                for (int r = 0; r < 4; ++r) v[r] = acc[nt][r] + bias;
#pragma unroll
                for (int r = 0; r < 4; ++r) {
                    int row = n0 + w * 16 + quad * 4 + r;
                    g_xl[(size_t)row * D + col] = rnd16(v[r]);
                }
#pragma unroll
                for (int r = 0; r < 4; r += 2) {
                    u32 pk = __builtin_amdgcn_cvt_pk_fp8_f32(v[r], v[r + 1], 0, false);
                    int row = n0 + w * 16 + quad * 4 + r;
                    g_xl8[(size_t)row * D + col] = (u8)(pk & 0xffu);
                    g_xl8[(size_t)(row + 1) * D + col] = (u8)((pk >> 8) & 0xffu);
                }
            }
        } else {
            u8* out8 = (wsel <= R) ? g_P8 + (size_t)(wsel - 1) * NN * D
                                   : g_Q8 + (size_t)(wsel - 1 - R) * NN * D;
#pragma unroll
            for (int nt = 0; nt < 8; ++nt) {
                int col = nt * 16 + mrow;
#pragma unroll
                for (int r = 0; r < 4; r += 2) {
                    u32 pk = __builtin_amdgcn_cvt_pk_fp8_f32(acc[nt][r], acc[nt][r + 1], 0, false);
                    int row = n0 + w * 16 + quad * 4 + r;
                    out8[(size_t)row * D + col] = (u8)(pk & 0xffu);
                    out8[(size_t)(row + 1) * D + col] = (u8)((pk >> 8) & 0xffu);
                }
            }
        }
    }
}

// ---- fused edge kernel: 1 tile/wave (r3 shape), re-partitioned edge order ----
// block = 64 list positions (4 waves x 16 edges); grid NE/64
// Edges arrive bucketed by re (dst-order preserved): P8 gathers hit one
// 4.2MB slab per phase. exp(logit) scatter-written to original CSR pos.
__global__ __launch_bounds__(256) void k_edge(const float* __restrict__ att, int wbase) {
    const int tid = threadIdx.x;
    const int e0 = blockIdx.x * 64;
    const int l = tid & 63, w = tid >> 6;
    const int mrow = l & 15, quad = l >> 4;
    const int myrow = w * 16 + mrow;
    const u16* BF = g_WnF + (size_t)(wbase + 11) * 2048 * 8;

    const int se = g_hse[e0 + myrow];
    const int de = g_hde[e0 + myrow];
    const int re = (int)(g_hpr[e0 + myrow] >> 24);

    // fp8 identity B-frags (e4m3 1.0 = 0x38), one byte set per contributing lane.
    const int pos8 = (mrow & 7) * 8;
    const i64 bev8 = (quad == (mrow >> 3))     ? (i64)(0x38LL << pos8) : 0LL;
    const i64 bod8 = (quad == 2 + (mrow >> 3)) ? (i64)(0x38LL << pos8) : 0LL;

    const u8* Prow = g_P8 + ((size_t)re * NN + se) * D;
    const u8* Qrow = g_Q8 + ((size_t)re * NN + de) * D;
    const u8* Xs = g_xl8 + (size_t)se * D;
    const u8* Xd = g_xl8 + (size_t)de * D;
    union { u32 u[4]; s8v v; } af[4];
    uint2 su[4], du[4];
#pragma unroll
    for (int s = 0; s < 4; ++s) {
        int c0 = s * 32 + quad * 8;
        uint2 pu = *(const uint2*)&Prow[c0];
        uint2 qu = *(const uint2*)&Qrow[c0];
        su[s] = *(const uint2*)&Xs[c0];
        du[s] = *(const uint2*)&Xd[c0];
        f2v pq0 = __builtin_amdgcn_cvt_pk_f32_fp8(pu.x, false) + __builtin_amdgcn_cvt_pk_f32_fp8(qu.x, false);
        f2v pq1 = __builtin_amdgcn_cvt_pk_f32_fp8(pu.x, true)  + __builtin_amdgcn_cvt_pk_f32_fp8(qu.x, true);
        f2v pq2 = __builtin_amdgcn_cvt_pk_f32_fp8(pu.y, false) + __builtin_amdgcn_cvt_pk_f32_fp8(qu.y, false);
        f2v pq3 = __builtin_amdgcn_cvt_pk_f32_fp8(pu.y, true)  + __builtin_amdgcn_cvt_pk_f32_fp8(qu.y, true);
        f2v g0 = gelu_pk(pq0), g1 = gelu_pk(pq1), g2 = gelu_pk(pq2), g3 = gelu_pk(pq3);
        af[s].u[0] = pack2r(g0.x, g0.y);
        af[s].u[1] = pack2r(g1.x, g1.y);
        af[s].u[2] = pack2r(g2.x, g2.y);
        af[s].u[3] = pack2r(g3.x, g3.y);
    }

    f4v acc[8];
#pragma unroll
    for (int nt = 0; nt < 8; ++nt) acc[nt] = (f4v){0.f, 0.f, 0.f, 0.f};
#pragma unroll
    for (int s = 0; s < 4; ++s) {
#pragma unroll
        for (int nt = 0; nt < 8; ++nt) {
            s8v b = *(const s8v*)&BF[(size_t)((s * 8 + nt) * 64 + l) * 8];
            acc[nt] = __builtin_amdgcn_mfma_f32_16x16x32_bf16(af[s].v, b, acc[nt], 0, 0, 0);
        }
        const i64 as = (i64)(((unsigned long long)su[s].y << 32) | su[s].x);
        const i64 ad = (i64)(((unsigned long long)du[s].y << 32) | du[s].x);
        acc[2 * s]     = __builtin_amdgcn_mfma_f32_16x16x32_fp8_fp8(as, bev8, acc[2 * s], 0, 0, 0);
        acc[2 * s]     = __builtin_amdgcn_mfma_f32_16x16x32_fp8_fp8(ad, bev8, acc[2 * s], 0, 0, 0);
        acc[2 * s + 1] = __builtin_amdgcn_mfma_f32_16x16x32_fp8_fp8(as, bod8, acc[2 * s + 1], 0, 0, 0);
        acc[2 * s + 1] = __builtin_amdgcn_mfma_f32_16x16x32_fp8_fp8(ad, bod8, acc[2 * s + 1], 0, 0, 0);
    }

    // epilogue in C-layout: edge (list idx) = e0 + w*16 + quad*4 + r, col = nt*16 + mrow
    float hsum[4][4];
#pragma unroll
    for (int r = 0; r < 4; ++r)
#pragma unroll
        for (int h = 0; h < 4; ++h) hsum[r][h] = 0.f;
#pragma unroll
    for (int nt = 0; nt < 8; ++nt) {
        int col = nt * 16 + mrow;
        float av = att[col];
        int h = nt >> 1;
#pragma unroll
        for (int r = 0; r < 4; ++r) {
            float m = acc[nt][r];
            float lr = fmaxf(m, 0.2f * m);   // leaky_relu, slope 0.2
            hsum[r][h] = fmaf(lr, av, hsum[r][h]);
        }
    }
#pragma unroll
    for (int r = 0; r < 4; ++r)
#pragma unroll
        for (int h = 0; h < 4; ++h) hsum[r][h] = rsum16(hsum[r][h]);
    if ((mrow & 3) == 0) {   // store exp(logit) at ORIGINAL CSR position
        int r = mrow >> 2;
        int cpos = (int)(g_hpr[e0 + w * 16 + quad * 4 + r] & 0xFFFFFFu);
        float4 v = make_float4(__expf(fminf(hsum[r][0], 80.f)),
                               __expf(fminf(hsum[r][1], 80.f)),
                               __expf(fminf(hsum[r][2], 80.f)),
                               __expf(fminf(hsum[r][3], 80.f)));
        *(float4*)&g_araw[(size_t)cpos * H] = v;
    }
}

// ---- fused gather: single-pass aggregate over pre-computed exp(logit) ----
// one wave per dst; block 256 = 4 dsts; grid NN/4; 8-deep unroll (r6, kept)
__global__ __launch_bounds__(256) void k_gath(const float* __restrict__ bias,
                                              int do_gelu) {
    const int lane = threadIdx.x & 63;
    const int d = blockIdx.x * 4 + (threadIdx.x >> 6);
    const int off = g_off[d];
    const int deg = g_off[d + 1] - off;
    const int h = lane >> 4;        // head for cols 2*lane, 2*lane+1

    const int* __restrict__ srcs = g_se + off;
    const float* __restrict__ ar = g_araw + (size_t)off * H + h;
    float a0 = 0.f, a1 = 0.f, dn = 0.f;
    int p = 0;
    for (; p + 8 <= deg; p += 8) {
        int ss[8];
#pragma unroll
        for (int j = 0; j < 8; ++j) ss[j] = srcs[p + j];
        u32 ww[8];
#pragma unroll
        for (int j = 0; j < 8; ++j) ww[j] = *(const u32*)&g_xl[(size_t)ss[j] * D + lane * 2];
        float cc[8];
#pragma unroll
        for (int j = 0; j < 8; ++j) cc[j] = ar[(p + j) * H];
#pragma unroll
        for (int j = 0; j < 8; ++j) {
            dn += cc[j];
            a0 = fmaf(bflo(ww[j]), cc[j], a0);
            a1 = fmaf(bfhi(ww[j]), cc[j], a1);
        }
    }
    for (; p + 4 <= deg; p += 4) {
        int s0 = srcs[p], s1 = srcs[p + 1], s2 = srcs[p + 2], s3 = srcs[p + 3];
        u32 w0 = *(const u32*)&g_xl[(size_t)s0 * D + lane * 2];
        u32 w1 = *(const u32*)&g_xl[(size_t)s1 * D + lane * 2];
        u32 w2 = *(const u32*)&g_xl[(size_t)s2 * D + lane * 2];
        u32 w3 = *(const u32*)&g_xl[(size_t)s3 * D + lane * 2];
        float c0 = ar[(p + 0) * H];
        float c1 = ar[(p + 1) * H];
        float c2 = ar[(p + 2) * H];
        float c3 = ar[(p + 3) * H];
        dn += (c0 + c1) + (c2 + c3);
        a0 = fmaf(bflo(w0), c0, a0); a1 = fmaf(bfhi(w0), c0, a1);
        a0 = fmaf(bflo(w1), c1, a0); a1 = fmaf(bfhi(w1), c1, a1);
        a0 = fmaf(bflo(w2), c2, a0); a1 = fmaf(bfhi(w2), c2, a1);
        a0 = fmaf(bflo(w3), c3, a0); a1 = fmaf(bfhi(w3), c3, a1);
    }
    for (; p < deg; ++p) {
        int s = srcs[p];
        u32 w = *(const u32*)&g_xl[(size_t)s * D + lane * 2];
        float cf = ar[p * H];
        dn += cf;
        a0 = fmaf(bflo(w), cf, a0);
        a1 = fmaf(bfhi(w), cf, a1);
    }
    const float inv = __builtin_amdgcn_rcpf(dn + 1e-16f);
    float v0 = a0 * inv + bias[lane * 2];
    float v1 = a1 * inv + bias[lane * 2 + 1];
    if (do_gelu) { v0 = gelu_f(v0); v1 = gelu_f(v1); }
    ((u32*)g_x)[(size_t)d * (D / 2) + lane] = pack2r(v0, v1);
}

// ---- output head (MFMA, LDS-free): y = x[:BS]@out_w + out_b; LayerNorm ----
__global__ __launch_bounds__(256) void k_head(const float* __restrict__ ob,
                                              const float* __restrict__ g,
                                              const float* __restrict__ b,
                                              float* __restrict__ out) {
    const int tid = threadIdx.x;
    const int r0 = blockIdx.x * 64;
    const int l = tid & 63, w = tid >> 6;
    const int mrow = l & 15, quad = l >> 4;
    const u16* xrow = g_x + (size_t)(r0 + w * 16 + mrow) * D;
    const u16* BF = g_WnF + (size_t)12 * 2048 * 8;

    f4v acc[8];
#pragma unroll
    for (int nt = 0; nt < 8; ++nt) acc[nt] = (f4v){0.f, 0.f, 0.f, 0.f};
#pragma unroll
    for (int s = 0; s < 4; ++s) {
        s8v a = *(const s8v*)&xrow[s * 32 + quad * 8];
#pragma unroll
        for (int nt = 0; nt < 8; ++nt) {
            s8v bb = *(const s8v*)&BF[(size_t)((s * 8 + nt) * 64 + l) * 8];
            acc[nt] = __builtin_amdgcn_mfma_f32_16x16x32_bf16(a, bb, acc[nt], 0, 0, 0);
        }
    }

    float sum[4] = {0.f, 0.f, 0.f, 0.f};
#pragma unroll
    for (int nt = 0; nt < 8; ++nt) {
        float obv = ob[nt * 16 + mrow];
#pragma unroll
        for (int r = 0; r < 4; ++r) {
            acc[nt][r] += obv;
            sum[r] += acc[nt][r];
        }
    }
    float mu[4];
#pragma unroll
    for (int r = 0; r < 4; ++r) mu[r] = rsum16(sum[r]) * (1.f / D);
    float sq[4] = {0.f, 0.f, 0.f, 0.f};
#pragma unroll
    for (int nt = 0; nt < 8; ++nt)
#pragma unroll
        for (int r = 0; r < 4; ++r) {
            float dv = acc[nt][r] - mu[r];
            sq[r] += dv * dv;
        }
    float rs[4];
#pragma unroll
    for (int r = 0; r < 4; ++r) rs[r] = rsqrtf(rsum16(sq[r]) * (1.f / D) + 1e-12f);
#pragma unroll
    for (int nt = 0; nt < 8; ++nt) {
        int col = nt * 16 + mrow;
        float gv = g[col], bv = b[col];
#pragma unroll
        for (int r = 0; r < 4; ++r) {
            int row = r0 + w * 16 + quad * 4 + r;
            out[(size_t)row * D + col] = (acc[nt][r] - mu[r]) * rs[r] * gv + bv;
        }
    }
}

extern "C" void kernel_launch(void* const* d_in, const int* in_sizes, int n_in,
                              void* d_out, int out_size, void* d_ws, size_t ws_size,
                              hipStream_t stream) {
    (void)in_sizes; (void)n_in; (void)out_size; (void)d_ws; (void)ws_size;
    const float* embs = (const float*)d_in[0];
    const int*   ei   = (const int*)d_in[1];
    const int*   et   = (const int*)d_in[2];
    const float* rel  = (const float*)d_in[3];
    const float* wl[2]   = { (const float*)d_in[4],  (const float*)d_in[9]  };
    const float* bl[2]   = { (const float*)d_in[5],  (const float*)d_in[10] };
    const float* we[2]   = { (const float*)d_in[6],  (const float*)d_in[11] };
    const float* attw[2] = { (const float*)d_in[7],  (const float*)d_in[12] };
    const float* bs[2]   = { (const float*)d_in[8],  (const float*)d_in[13] };
    const float* ow  = (const float*)d_in[14];
    const float* ob  = (const float*)d_in[15];
    const float* lng = (const float*)d_in[16];
    const float* lnb = (const float*)d_in[17];
    float* out = (float*)d_out;

    k_cvt<<<NN * D / 512, 256, 0, stream>>>(embs);

    // weight prep for BOTH layers up front (overlaps CSR build)
    for (int l = 0; l < 2; ++l) {
        const float* Rm = rel + (size_t)l * R * 2 * D * D;
        k_prep<<<dim3(2048 / 256, 13), 256, 0, stream>>>(wl[l], Rm, we[l], ow, l * 13);
    }

    // CSR by dst (edge list shared by both layers)
    k_zcnt<<<NN / 256, 256, 0, stream>>>();
    k_count<<<NE / 256, 256, 0, stream>>>(ei);
    k_scan<<<1, 1024, 0, stream>>>();
    k_scatter<<<NE / 256, 256, 0, stream>>>(ei, et);

    // stable partition by relation (reused by both layers)
    k_phist<<<NB, 256, 0, stream>>>();
    k_pscan<<<1, 1024, 0, stream>>>();
    k_pscat<<<NB, 256, 0, stream>>>();

    for (int l = 0; l < 2; ++l) {
        k_node<<<dim3(NN / 64, 4), 256, 0, stream>>>(bl[l], l * 13);
        k_edge<<<NE / 64, 256, 0, stream>>>(attw[l], l * 13);
        k_gath<<<NN / 4, 256, 0, stream>>>(bs[l], l == 0 ? 1 : 0);
    }

    k_head<<<BS / 64, 256, 0, stream>>>(ob, lng, lnb, out);
}

// Round 9
// 463.985 us; speedup vs baseline: 1.0601x; 1.0601x over previous
//
#include <hip/hip_runtime.h>
#include <hip/hip_bf16.h>

typedef __hip_bfloat16 bf16;
typedef __attribute__((ext_vector_type(8))) short s8v;
typedef __attribute__((ext_vector_type(4))) float f4v;
typedef __attribute__((ext_vector_type(2))) float f2v;
typedef unsigned short u16;
typedef unsigned int u32;
typedef unsigned char u8;
typedef long long i64;

#define NN 32768
#define NE 524288
#define D 128
#define H 4
#define C 32
#define R 5
#define BS 8192

__device__ __forceinline__ u16 f2bs(float x) { bf16 h = __float2bfloat16(x); return *(u16*)&h; }
__device__ __forceinline__ float bflo(u32 u) { return __uint_as_float(u << 16); }
__device__ __forceinline__ float bfhi(u32 u) { return __uint_as_float(u & 0xffff0000u); }
// fast bf16 pair pack: round-half-up (+0x8000) then byte-perm; 3 VALU instrs
__device__ __forceinline__ u32 pack2r(float a, float b) {
    u32 ua = __float_as_uint(a) + 0x8000u;
    u32 ub = __float_as_uint(b) + 0x8000u;
    return __builtin_amdgcn_perm(ub, ua, 0x07060302u);   // lo16=hi(a), hi16=hi(b)
}
__device__ __forceinline__ u16 rnd16(float a) {
    return (u16)((__float_as_uint(a) + 0x8000u) >> 16);
}
__device__ __forceinline__ float gelu_f(float x) {   // exact (value-path epilogue use)
    return 0.5f * x * (1.f + erff(x * 0.7071067811865475f));
}
// polynomial gelu on a packed f32 pair (logit path only):
// erf(t/sqrt2) ~ t*poly(t^2), t=clamp(x,-4,4); max |err| ~6.6e-3 near |x|~2.5.
__device__ __forceinline__ f2v gelu_pk(f2v x) {
    f2v t;
    t.x = fminf(fmaxf(x.x, -4.f), 4.f);   // v_med3_f32
    t.y = fminf(fmaxf(x.y, -4.f), 4.f);
    f2v s = t * t;
    f2v h = __builtin_elementwise_fma(s, (f2v)1.53421e-5f, (f2v)-7.13918e-4f);
    h = __builtin_elementwise_fma(s, h, (f2v)0.0129194f);
    h = __builtin_elementwise_fma(s, h, (f2v)-0.1207967f);
    h = __builtin_elementwise_fma(s, h, (f2v)0.794118f);
    f2v e = t * h;                         // ~erf(x/sqrt2)
    f2v hx = x * 0.5f;
    return __builtin_elementwise_fma(hx, e, hx);   // 0.5x + 0.5x*erf
}
// DPP rotate-add reduction across the 16 lanes of a DPP row (lanes 16q..16q+15).
template <int CTRL>
__device__ __forceinline__ float dpp_add(float v) {
    int t = __builtin_amdgcn_update_dpp(0, __float_as_int(v), CTRL, 0xf, 0xf, true);
    return v + __int_as_float(t);
}
__device__ __forceinline__ float rsum16(float v) {
    v = dpp_add<0x128>(v);   // row_ror:8
    v = dpp_add<0x124>(v);   // row_ror:4
    v = dpp_add<0x122>(v);   // row_ror:2
    v = dpp_add<0x121>(v);   // row_ror:1
    return v;
}

// ---- static device scratch ----
__device__ u16      g_x[NN * D];          // bf16 working activations
__device__ float    g_araw[NE * H];       // exp(logit), CSR-position indexed
__device__ u8       g_P8[R * NN * D];     // fp8 e4m3: x @ Rtop[r]   (logit path)
__device__ u8       g_Q8[R * NN * D];     // fp8 e4m3: x @ Rbot[r]   (logit path)
__device__ u16      g_xl[NN * D];         // bf16: x @ Wl + bl       (value path)
__device__ u8       g_xl8[NN * D];        // fp8 copy of xl          (logit path)
__device__ u16      g_WnF[26 * 2048 * 8]; // bf16 weights, MFMA B-frag order
__device__ int      g_cnt[NN];            // CSR: in-degree counts
__device__ int      g_cur[NN];            // CSR: scatter cursors
__device__ int      g_off[NN + 1];        // CSR: row offsets (by dst)
__device__ int      g_se[NE];             // CSR-ordered src node ids
__device__ int      g_de[NE];             // CSR-ordered dst node ids
__device__ int      g_re[NE];             // CSR-ordered relation ids

// fused init: blocks [0, NN*D/512) convert embs -> bf16; the tail zeroes CSR counters
__global__ void k_init(const float* __restrict__ e) {
    int b = blockIdx.x;
    if (b < NN * D / 512) {
        int i = b * 256 + threadIdx.x;   // NN*D/2 threads
        float2 v = *(const float2*)&e[(size_t)i * 2];
        ((u32*)g_x)[i] = pack2r(v.x, v.y);
    } else {
        int i = (b - NN * D / 512) * 256 + threadIdx.x;   // NN threads
        g_cnt[i] = 0; g_cur[i] = 0;
    }
}

// ---- CSR build (edge list identical for both layers: build once) ----
__global__ void k_count(const int* __restrict__ ei) {
    int i = blockIdx.x * 256 + threadIdx.x;   // NE threads
    atomicAdd(&g_cnt[ei[NE + i]], 1);
}
__global__ void k_scan() {   // 1 block, 1024 threads, 32 elems each
    __shared__ int sums[1024];
    const int t = threadIdx.x;
    const int base = t * 32;
    int local[32];
    int s = 0;
#pragma unroll
    for (int i = 0; i < 32; ++i) { local[i] = s; s += g_cnt[base + i]; }
    sums[t] = s;
    __syncthreads();
    for (int off = 1; off < 1024; off <<= 1) {
        int v = (t >= off) ? sums[t - off] : 0;
        __syncthreads();
        sums[t] += v;
        __syncthreads();
    }
    int chunkoff = (t == 0) ? 0 : sums[t - 1];
#pragma unroll
    for (int i = 0; i < 32; ++i) g_off[base + i] = chunkoff + local[i];
    if (t == 1023) g_off[NN] = sums[1023];
}
__global__ void k_scatter(const int* __restrict__ ei, const int* __restrict__ et) {
    int i = blockIdx.x * 256 + threadIdx.x;   // NE threads
    int d = ei[NE + i];
    int pos = g_off[d] + atomicAdd(&g_cur[d], 1);
    g_se[pos] = ei[i];
    g_de[pos] = d;
    g_re[pos] = et[i];
}

// ---- weights -> bf16 MFMA B-fragment order (one layer, 13 matrices) ----
__global__ void k_prep(const float* __restrict__ Wl, const float* __restrict__ Rm,
                       const float* __restrict__ We, const float* __restrict__ Ow,
                       int base) {
    int f = blockIdx.x * 256 + threadIdx.x;   // frag id 0..2047
    int y = blockIdx.y;
    const float* src;
    if (y == 0) src = Wl;
    else if (y <= R) src = Rm + (size_t)(y - 1) * 2 * D * D;
    else if (y <= 2 * R) src = Rm + (size_t)(y - 1 - R) * 2 * D * D + D * D;
    else if (y == 11) src = We;
    else src = Ow;
    int lane = f & 63, nt = (f >> 6) & 7, s = f >> 9;
    int n = nt * 16 + (lane & 15);
    int ks = s * 32 + (lane >> 4) * 8;
    u16 tmp[8];
#pragma unroll
    for (int j = 0; j < 8; ++j) tmp[j] = f2bs(src[(size_t)(ks + j) * D + n]);
    *(uint4*)&g_WnF[((size_t)(base + y) * 2048 + f) * 8] = *(uint4*)tmp;
}

// ---- node transforms (MFMA, LDS-free): xl (bf16+fp8) / P[r],Q[r] (fp8) ----
// fused wsel groups: blockIdx.y in {0..3} covers wsel {0-2,3-5,6-8,9-10};
// A-fragments loaded once per group (r6).
__global__ __launch_bounds__(256) void k_node(const float* __restrict__ bl, int wbase) {
    const int tid = threadIdx.x;
    const int n0 = blockIdx.x * 64;
    const int wstart = blockIdx.y * 3;              // 0,3,6,9
    const int wend = (wstart + 3 < 11) ? wstart + 3 : 11;
    const int l = tid & 63, w = tid >> 6;
    const int mrow = l & 15, quad = l >> 4;
    const u16* xrow = g_x + (size_t)(n0 + w * 16 + mrow) * D;

    s8v a[4];
#pragma unroll
    for (int s = 0; s < 4; ++s) a[s] = *(const s8v*)&xrow[s * 32 + quad * 8];

    for (int wsel = wstart; wsel < wend; ++wsel) {
        const u16* BF = g_WnF + (size_t)(wbase + wsel) * 2048 * 8;
        f4v acc[8];
#pragma unroll
        for (int nt = 0; nt < 8; ++nt) acc[nt] = (f4v){0.f, 0.f, 0.f, 0.f};
#pragma unroll
        for (int s = 0; s < 4; ++s) {
#pragma unroll
            for (int nt = 0; nt < 8; ++nt) {
                s8v b = *(const s8v*)&BF[(size_t)((s * 8 + nt) * 64 + l) * 8];
                acc[nt] = __builtin_amdgcn_mfma_f32_16x16x32_bf16(a[s], b, acc[nt], 0, 0, 0);
            }
        }

        if (wsel == 0) {
#pragma unroll
            for (int nt = 0; nt < 8; ++nt) {
                int col = nt * 16 + mrow;
                float bias = bl[col];
                float v[4];
#pragma unroll
                for (int r = 0; r < 4; ++r) v[r] = acc[nt][r] + bias;
#pragma unroll
                for (int r = 0; r < 4; ++r) {
                    int row = n0 + w * 16 + quad * 4 + r;
                    g_xl[(size_t)row * D + col] = rnd16(v[r]);
                }
#pragma unroll
                for (int r = 0; r < 4; r += 2) {
                    u32 pk = __builtin_amdgcn_cvt_pk_fp8_f32(v[r], v[r + 1], 0, false);
                    int row = n0 + w * 16 + quad * 4 + r;
                    g_xl8[(size_t)row * D + col] = (u8)(pk & 0xffu);
                    g_xl8[(size_t)(row + 1) * D + col] = (u8)((pk >> 8) & 0xffu);
                }
            }
        } else {
            u8* out8 = (wsel <= R) ? g_P8 + (size_t)(wsel - 1) * NN * D
                                   : g_Q8 + (size_t)(wsel - 1 - R) * NN * D;
#pragma unroll
            for (int nt = 0; nt < 8; ++nt) {
                int col = nt * 16 + mrow;
#pragma unroll
                for (int r = 0; r < 4; r += 2) {
                    u32 pk = __builtin_amdgcn_cvt_pk_fp8_f32(acc[nt][r], acc[nt][r + 1], 0, false);
                    int row = n0 + w * 16 + quad * 4 + r;
                    out8[(size_t)row * D + col] = (u8)(pk & 0xffu);
                    out8[(size_t)(row + 1) * D + col] = (u8)((pk >> 8) & 0xffu);
                }
            }
        }
    }
}

// ---- fused edge kernel: 1 tile/wave (r3/r6 shape -- verified optimum) ----
// block = 64 CSR positions (4 waves x 16 edges); grid NE/64
// Lessons held: VGPR <= 64 (8 waves/SIMD tier) -- TLP hides gather latency
// (r5: 2-tile ILP regressed); relation-partitioning doesn't beat the
// latency floor (r7: FETCH -8%, dur -2%, partition overhead +14us).
__global__ __launch_bounds__(256) void k_edge(const float* __restrict__ att, int wbase) {
    const int tid = threadIdx.x;
    const int e0 = blockIdx.x * 64;
    const int l = tid & 63, w = tid >> 6;
    const int mrow = l & 15, quad = l >> 4;
    const int myrow = w * 16 + mrow;
    const u16* BF = g_WnF + (size_t)(wbase + 11) * 2048 * 8;

    const int se = g_se[e0 + myrow];
    const int de = g_de[e0 + myrow];
    const int re = g_re[e0 + myrow];

    // fp8 identity B-frags (e4m3 1.0 = 0x38), one byte set per contributing lane.
    const int pos8 = (mrow & 7) * 8;
    const i64 bev8 = (quad == (mrow >> 3))     ? (i64)(0x38LL << pos8) : 0LL;
    const i64 bod8 = (quad == 2 + (mrow >> 3)) ? (i64)(0x38LL << pos8) : 0LL;

    const u8* Prow = g_P8 + ((size_t)re * NN + se) * D;
    const u8* Qrow = g_Q8 + ((size_t)re * NN + de) * D;
    const u8* Xs = g_xl8 + (size_t)se * D;
    const u8* Xd = g_xl8 + (size_t)de * D;
    union { u32 u[4]; s8v v; } af[4];
    uint2 su[4], du[4];
#pragma unroll
    for (int s = 0; s < 4; ++s) {
        int c0 = s * 32 + quad * 8;
        uint2 pu = *(const uint2*)&Prow[c0];
        uint2 qu = *(const uint2*)&Qrow[c0];
        su[s] = *(const uint2*)&Xs[c0];
        du[s] = *(const uint2*)&Xd[c0];
        f2v pq0 = __builtin_amdgcn_cvt_pk_f32_fp8(pu.x, false) + __builtin_amdgcn_cvt_pk_f32_fp8(qu.x, false);
        f2v pq1 = __builtin_amdgcn_cvt_pk_f32_fp8(pu.x, true)  + __builtin_amdgcn_cvt_pk_f32_fp8(qu.x, true);
        f2v pq2 = __builtin_amdgcn_cvt_pk_f32_fp8(pu.y, false) + __builtin_amdgcn_cvt_pk_f32_fp8(qu.y, false);
        f2v pq3 = __builtin_amdgcn_cvt_pk_f32_fp8(pu.y, true)  + __builtin_amdgcn_cvt_pk_f32_fp8(qu.y, true);
        f2v g0 = gelu_pk(pq0), g1 = gelu_pk(pq1), g2 = gelu_pk(pq2), g3 = gelu_pk(pq3);
        af[s].u[0] = pack2r(g0.x, g0.y);
        af[s].u[1] = pack2r(g1.x, g1.y);
        af[s].u[2] = pack2r(g2.x, g2.y);
        af[s].u[3] = pack2r(g3.x, g3.y);
    }

    f4v acc[8];
#pragma unroll
    for (int nt = 0; nt < 8; ++nt) acc[nt] = (f4v){0.f, 0.f, 0.f, 0.f};
#pragma unroll
    for (int s = 0; s < 4; ++s) {
#pragma unroll
        for (int nt = 0; nt < 8; ++nt) {
            s8v b = *(const s8v*)&BF[(size_t)((s * 8 + nt) * 64 + l) * 8];
            acc[nt] = __builtin_amdgcn_mfma_f32_16x16x32_bf16(af[s].v, b, acc[nt], 0, 0, 0);
        }
        const i64 as = (i64)(((unsigned long long)su[s].y << 32) | su[s].x);
        const i64 ad = (i64)(((unsigned long long)du[s].y << 32) | du[s].x);
        acc[2 * s]     = __builtin_amdgcn_mfma_f32_16x16x32_fp8_fp8(as, bev8, acc[2 * s], 0, 0, 0);
        acc[2 * s]     = __builtin_amdgcn_mfma_f32_16x16x32_fp8_fp8(ad, bev8, acc[2 * s], 0, 0, 0);
        acc[2 * s + 1] = __builtin_amdgcn_mfma_f32_16x16x32_fp8_fp8(as, bod8, acc[2 * s + 1], 0, 0, 0);
        acc[2 * s + 1] = __builtin_amdgcn_mfma_f32_16x16x32_fp8_fp8(ad, bod8, acc[2 * s + 1], 0, 0, 0);
    }

    // epilogue in C-layout: edge = w*16 + quad*4 + r, col = nt*16 + mrow
    float hsum[4][4];
#pragma unroll
    for (int r = 0; r < 4; ++r)
#pragma unroll
        for (int h = 0; h < 4; ++h) hsum[r][h] = 0.f;
#pragma unroll
    for (int nt = 0; nt < 8; ++nt) {
        int col = nt * 16 + mrow;
        float av = att[col];
        int h = nt >> 1;
#pragma unroll
        for (int r = 0; r < 4; ++r) {
            float m = acc[nt][r];
            float lr = fmaxf(m, 0.2f * m);   // leaky_relu, slope 0.2
            hsum[r][h] = fmaf(lr, av, hsum[r][h]);
        }
    }
#pragma unroll
    for (int r = 0; r < 4; ++r)
#pragma unroll
        for (int h = 0; h < 4; ++h) hsum[r][h] = rsum16(hsum[r][h]);
    if ((mrow & 3) == 0) {   // store exp(logit) directly
        int r = mrow >> 2;
        float4 v = make_float4(__expf(fminf(hsum[r][0], 80.f)),
                               __expf(fminf(hsum[r][1], 80.f)),
                               __expf(fminf(hsum[r][2], 80.f)),
                               __expf(fminf(hsum[r][3], 80.f)));
        *(float4*)&g_araw[(size_t)(e0 + w * 16 + quad * 4 + r) * H] = v;
    }
}

// ---- fused gather: single-pass aggregate over pre-computed exp(logit) ----
// one wave per dst; block 256 = 4 dsts; grid NN/4; 8-deep unroll (r6)
__global__ __launch_bounds__(256) void k_gath(const float* __restrict__ bias,
                                              int do_gelu) {
    const int lane = threadIdx.x & 63;
    const int d = blockIdx.x * 4 + (threadIdx.x >> 6);
    const int off = g_off[d];
    const int deg = g_off[d + 1] - off;
    const int h = lane >> 4;        // head for cols 2*lane, 2*lane+1

    const int* __restrict__ srcs = g_se + off;
    const float* __restrict__ ar = g_araw + (size_t)off * H + h;
    float a0 = 0.f, a1 = 0.f, dn = 0.f;
    int p = 0;
    for (; p + 8 <= deg; p += 8) {
        int ss[8];
#pragma unroll
        for (int j = 0; j < 8; ++j) ss[j] = srcs[p + j];
        u32 ww[8];
#pragma unroll
        for (int j = 0; j < 8; ++j) ww[j] = *(const u32*)&g_xl[(size_t)ss[j] * D + lane * 2];
        float cc[8];
#pragma unroll
        for (int j = 0; j < 8; ++j) cc[j] = ar[(p + j) * H];
#pragma unroll
        for (int j = 0; j < 8; ++j) {
            dn += cc[j];
            a0 = fmaf(bflo(ww[j]), cc[j], a0);
            a1 = fmaf(bfhi(ww[j]), cc[j], a1);
        }
    }
    for (; p + 4 <= deg; p += 4) {
        int s0 = srcs[p], s1 = srcs[p + 1], s2 = srcs[p + 2], s3 = srcs[p + 3];
        u32 w0 = *(const u32*)&g_xl[(size_t)s0 * D + lane * 2];
        u32 w1 = *(const u32*)&g_xl[(size_t)s1 * D + lane * 2];
        u32 w2 = *(const u32*)&g_xl[(size_t)s2 * D + lane * 2];
        u32 w3 = *(const u32*)&g_xl[(size_t)s3 * D + lane * 2];
        float c0 = ar[(p + 0) * H];
        float c1 = ar[(p + 1) * H];
        float c2 = ar[(p + 2) * H];
        float c3 = ar[(p + 3) * H];
        dn += (c0 + c1) + (c2 + c3);
        a0 = fmaf(bflo(w0), c0, a0); a1 = fmaf(bfhi(w0), c0, a1);
        a0 = fmaf(bflo(w1), c1, a0); a1 = fmaf(bfhi(w1), c1, a1);
        a0 = fmaf(bflo(w2), c2, a0); a1 = fmaf(bfhi(w2), c2, a1);
        a0 = fmaf(bflo(w3), c3, a0); a1 = fmaf(bfhi(w3), c3, a1);
    }
    for (; p < deg; ++p) {
        int s = srcs[p];
        u32 w = *(const u32*)&g_xl[(size_t)s * D + lane * 2];
        float cf = ar[p * H];
        dn += cf;
        a0 = fmaf(bflo(w), cf, a0);
        a1 = fmaf(bfhi(w), cf, a1);
    }
    const float inv = __builtin_amdgcn_rcpf(dn + 1e-16f);
    float v0 = a0 * inv + bias[lane * 2];
    float v1 = a1 * inv + bias[lane * 2 + 1];
    if (do_gelu) { v0 = gelu_f(v0); v1 = gelu_f(v1); }
    ((u32*)g_x)[(size_t)d * (D / 2) + lane] = pack2r(v0, v1);
}

// ---- output head (MFMA, LDS-free): y = x[:BS]@out_w + out_b; LayerNorm ----
__global__ __launch_bounds__(256) void k_head(const float* __restrict__ ob,
                                              const float* __restrict__ g,
                                              const float* __restrict__ b,
                                              float* __restrict__ out) {
    const int tid = threadIdx.x;
    const int r0 = blockIdx.x * 64;
    const int l = tid & 63, w = tid >> 6;
    const int mrow = l & 15, quad = l >> 4;
    const u16* xrow = g_x + (size_t)(r0 + w * 16 + mrow) * D;
    const u16* BF = g_WnF + (size_t)12 * 2048 * 8;

    f4v acc[8];
#pragma unroll
    for (int nt = 0; nt < 8; ++nt) acc[nt] = (f4v){0.f, 0.f, 0.f, 0.f};
#pragma unroll
    for (int s = 0; s < 4; ++s) {
        s8v a = *(const s8v*)&xrow[s * 32 + quad * 8];
#pragma unroll
        for (int nt = 0; nt < 8; ++nt) {
            s8v bb = *(const s8v*)&BF[(size_t)((s * 8 + nt) * 64 + l) * 8];
            acc[nt] = __builtin_amdgcn_mfma_f32_16x16x32_bf16(a, bb, acc[nt], 0, 0, 0);
        }
    }

    float sum[4] = {0.f, 0.f, 0.f, 0.f};
#pragma unroll
    for (int nt = 0; nt < 8; ++nt) {
        float obv = ob[nt * 16 + mrow];
#pragma unroll
        for (int r = 0; r < 4; ++r) {
            acc[nt][r] += obv;
            sum[r] += acc[nt][r];
        }
    }
    float mu[4];
#pragma unroll
    for (int r = 0; r < 4; ++r) mu[r] = rsum16(sum[r]) * (1.f / D);
    float sq[4] = {0.f, 0.f, 0.f, 0.f};
#pragma unroll
    for (int nt = 0; nt < 8; ++nt)
#pragma unroll
        for (int r = 0; r < 4; ++r) {
            float dv = acc[nt][r] - mu[r];
            sq[r] += dv * dv;
        }
    float rs[4];
#pragma unroll
    for (int r = 0; r < 4; ++r) rs[r] = rsqrtf(rsum16(sq[r]) * (1.f / D) + 1e-12f);
#pragma unroll
    for (int nt = 0; nt < 8; ++nt) {
        int col = nt * 16 + mrow;
        float gv = g[col], bv = b[col];
#pragma unroll
        for (int r = 0; r < 4; ++r) {
            int row = r0 + w * 16 + quad * 4 + r;
            out[(size_t)row * D + col] = (acc[nt][r] - mu[r]) * rs[r] * gv + bv;
        }
    }
}

extern "C" void kernel_launch(void* const* d_in, const int* in_sizes, int n_in,
                              void* d_out, int out_size, void* d_ws, size_t ws_size,
                              hipStream_t stream) {
    (void)in_sizes; (void)n_in; (void)out_size; (void)d_ws; (void)ws_size;
    const float* embs = (const float*)d_in[0];
    const int*   ei   = (const int*)d_in[1];
    const int*   et   = (const int*)d_in[2];
    const float* rel  = (const float*)d_in[3];
    const float* wl[2]   = { (const float*)d_in[4],  (const float*)d_in[9]  };
    const float* bl[2]   = { (const float*)d_in[5],  (const float*)d_in[10] };
    const float* we[2]   = { (const float*)d_in[6],  (const float*)d_in[11] };
    const float* attw[2] = { (const float*)d_in[7],  (const float*)d_in[12] };
    const float* bs[2]   = { (const float*)d_in[8],  (const float*)d_in[13] };
    const float* ow  = (const float*)d_in[14];
    const float* ob  = (const float*)d_in[15];
    const float* lng = (const float*)d_in[16];
    const float* lnb = (const float*)d_in[17];
    float* out = (float*)d_out;

    // fused: embs->bf16 convert + CSR counter zeroing (one launch)
    k_init<<<NN * D / 512 + NN / 256, 256, 0, stream>>>(embs);

    // weight prep for BOTH layers up front
    for (int l = 0; l < 2; ++l) {
        const float* Rm = rel + (size_t)l * R * 2 * D * D;
        k_prep<<<dim3(2048 / 256, 13), 256, 0, stream>>>(wl[l], Rm, we[l], ow, l * 13);
    }

    // CSR by dst (edge list shared by both layers)
    k_count<<<NE / 256, 256, 0, stream>>>(ei);
    k_scan<<<1, 1024, 0, stream>>>();
    k_scatter<<<NE / 256, 256, 0, stream>>>(ei, et);

    for (int l = 0; l < 2; ++l) {
        k_node<<<dim3(NN / 64, 4), 256, 0, stream>>>(bl[l], l * 13);
        k_edge<<<NE / 64, 256, 0, stream>>>(attw[l], l * 13);
        k_gath<<<NN / 4, 256, 0, stream>>>(bs[l], l == 0 ? 1 : 0);
    }

    k_head<<<BS / 64, 256, 0, stream>>>(ob, lng, lnb, out);
}

// Round 10
// 459.920 us; speedup vs baseline: 1.0695x; 1.0088x over previous
//
#include <hip/hip_runtime.h>
#include <hip/hip_bf16.h>

typedef __hip_bfloat16 bf16;
typedef __attribute__((ext_vector_type(8))) short s8v;
typedef __attribute__((ext_vector_type(4))) float f4v;
typedef __attribute__((ext_vector_type(2))) float f2v;
typedef unsigned short u16;
typedef unsigned int u32;
typedef unsigned char u8;
typedef long long i64;

#define NN 32768
#define NE 524288
#define D 128
#define H 4
#define C 32
#define R 5
#define BS 8192

__device__ __forceinline__ u16 f2bs(float x) { bf16 h = __float2bfloat16(x); return *(u16*)&h; }
__device__ __forceinline__ float bflo(u32 u) { return __uint_as_float(u << 16); }
__device__ __forceinline__ float bfhi(u32 u) { return __uint_as_float(u & 0xffff0000u); }
// fast bf16 pair pack: round-half-up (+0x8000) then byte-perm; 3 VALU instrs
__device__ __forceinline__ u32 pack2r(float a, float b) {
    u32 ua = __float_as_uint(a) + 0x8000u;
    u32 ub = __float_as_uint(b) + 0x8000u;
    return __builtin_amdgcn_perm(ub, ua, 0x07060302u);   // lo16=hi(a), hi16=hi(b)
}
__device__ __forceinline__ u16 rnd16(float a) {
    return (u16)((__float_as_uint(a) + 0x8000u) >> 16);
}
__device__ __forceinline__ float gelu_f(float x) {   // exact (value-path epilogue use)
    return 0.5f * x * (1.f + erff(x * 0.7071067811865475f));
}
// polynomial gelu on a packed f32 pair (logit path only):
// erf(t/sqrt2) ~ t*poly(t^2), t=clamp(x,-4,4); max |err| ~6.6e-3 near |x|~2.5.
__device__ __forceinline__ f2v gelu_pk(f2v x) {
    f2v t;
    t.x = fminf(fmaxf(x.x, -4.f), 4.f);   // v_med3_f32
    t.y = fminf(fmaxf(x.y, -4.f), 4.f);
    f2v s = t * t;
    f2v h = __builtin_elementwise_fma(s, (f2v)1.53421e-5f, (f2v)-7.13918e-4f);
    h = __builtin_elementwise_fma(s, h, (f2v)0.0129194f);
    h = __builtin_elementwise_fma(s, h, (f2v)-0.1207967f);
    h = __builtin_elementwise_fma(s, h, (f2v)0.794118f);
    f2v e = t * h;                         // ~erf(x/sqrt2)
    f2v hx = x * 0.5f;
    return __builtin_elementwise_fma(hx, e, hx);   // 0.5x + 0.5x*erf
}
// DPP rotate-add reduction across the 16 lanes of a DPP row (lanes 16q..16q+15).
template <int CTRL>
__device__ __forceinline__ float dpp_add(float v) {
    int t = __builtin_amdgcn_update_dpp(0, __float_as_int(v), CTRL, 0xf, 0xf, true);
    return v + __int_as_float(t);
}
__device__ __forceinline__ float rsum16(float v) {
    v = dpp_add<0x128>(v);   // row_ror:8
    v = dpp_add<0x124>(v);   // row_ror:4
    v = dpp_add<0x122>(v);   // row_ror:2
    v = dpp_add<0x121>(v);   // row_ror:1
    return v;
}

// ---- static device scratch ----
// P8/Q8 row layout is PERMUTED (R10): byte position p = 8*mrow + nt holds
// original ea-column 16*nt + mrow. Consumed only by k_edge's af path, whose
// We B-frags (k_prep y==11) carry the matching row permutation. xl/xl8 keep
// the original layout (identity-MFMA k -> output col must stay canonical).
__device__ u16      g_x[NN * D];          // bf16 working activations
__device__ float    g_araw[NE * H];       // exp(logit), CSR-position indexed
__device__ u8       g_P8[R * NN * D];     // fp8 e4m3: x @ Rtop[r]  (permuted rows)
__device__ u8       g_Q8[R * NN * D];     // fp8 e4m3: x @ Rbot[r]  (permuted rows)
__device__ u16      g_xl[NN * D];         // bf16: x @ Wl + bl       (value path)
__device__ u8       g_xl8[NN * D];        // fp8 copy of xl          (logit path)
__device__ u16      g_WnF[26 * 2048 * 8]; // bf16 weights, MFMA B-frag order
__device__ int      g_cnt[NN];            // CSR: in-degree counts
__device__ int      g_cur[NN];            // CSR: scatter cursors
__device__ int      g_off[NN + 1];        // CSR: row offsets (by dst)
__device__ int      g_se[NE];             // CSR-ordered src node ids
__device__ int      g_de[NE];             // CSR-ordered dst node ids
__device__ int      g_re[NE];             // CSR-ordered relation ids

// fused init: blocks [0, NN*D/512) convert embs -> bf16; the tail zeroes CSR counters
__global__ void k_init(const float* __restrict__ e) {
    int b = blockIdx.x;
    if (b < NN * D / 512) {
        int i = b * 256 + threadIdx.x;   // NN*D/2 threads
        float2 v = *(const float2*)&e[(size_t)i * 2];
        ((u32*)g_x)[i] = pack2r(v.x, v.y);
    } else {
        int i = (b - NN * D / 512) * 256 + threadIdx.x;   // NN threads
        g_cnt[i] = 0; g_cur[i] = 0;
    }
}

// ---- CSR build (edge list identical for both layers: build once) ----
__global__ void k_count(const int* __restrict__ ei) {
    int i = blockIdx.x * 256 + threadIdx.x;   // NE threads
    atomicAdd(&g_cnt[ei[NE + i]], 1);
}
__global__ void k_scan() {   // 1 block, 1024 threads, 32 elems each
    __shared__ int sums[1024];
    const int t = threadIdx.x;
    const int base = t * 32;
    int local[32];
    int s = 0;
#pragma unroll
    for (int i = 0; i < 32; ++i) { local[i] = s; s += g_cnt[base + i]; }
    sums[t] = s;
    __syncthreads();
    for (int off = 1; off < 1024; off <<= 1) {
        int v = (t >= off) ? sums[t - off] : 0;
        __syncthreads();
        sums[t] += v;
        __syncthreads();
    }
    int chunkoff = (t == 0) ? 0 : sums[t - 1];
#pragma unroll
    for (int i = 0; i < 32; ++i) g_off[base + i] = chunkoff + local[i];
    if (t == 1023) g_off[NN] = sums[1023];
}
__global__ void k_scatter(const int* __restrict__ ei, const int* __restrict__ et) {
    int i = blockIdx.x * 256 + threadIdx.x;   // NE threads
    int d = ei[NE + i];
    int pos = g_off[d] + atomicAdd(&g_cur[d], 1);
    g_se[pos] = ei[i];
    g_de[pos] = d;
    g_re[pos] = et[i];
}

// ---- weights -> bf16 MFMA B-fragment order (one layer, 13 matrices) ----
// y==11 (We): rows permuted to match P8/Q8's permuted feature order --
// B-frag k-slot (s, q=lane>>4, j) sources We row 16*j + 4*s + q, so the
// MFMA contraction against permuted ea reproduces the original product.
__global__ void k_prep(const float* __restrict__ Wl, const float* __restrict__ Rm,
                       const float* __restrict__ We, const float* __restrict__ Ow,
                       int base) {
    int f = blockIdx.x * 256 + threadIdx.x;   // frag id 0..2047
    int y = blockIdx.y;
    const float* src;
    if (y == 0) src = Wl;
    else if (y <= R) src = Rm + (size_t)(y - 1) * 2 * D * D;
    else if (y <= 2 * R) src = Rm + (size_t)(y - 1 - R) * 2 * D * D + D * D;
    else if (y == 11) src = We;
    else src = Ow;
    int lane = f & 63, nt = (f >> 6) & 7, s = f >> 9;
    int n = nt * 16 + (lane & 15);
    int q = lane >> 4;
    int ks = s * 32 + q * 8;
    u16 tmp[8];
#pragma unroll
    for (int j = 0; j < 8; ++j) {
        int krow = (y == 11) ? (16 * j + 4 * s + q) : (ks + j);
        tmp[j] = f2bs(src[(size_t)krow * D + n]);
    }
    *(uint4*)&g_WnF[((size_t)(base + y) * 2048 + f) * 8] = *(uint4*)tmp;
}

// ---- node transforms (MFMA, LDS-free): xl (bf16+fp8) / P[r],Q[r] (fp8) ----
// fused wsel groups (r6). R10: P8/Q8 epilogue writes the permuted row layout
// as ONE 8B store per row (4 cvt_pk_fp8 + 2 v_perm) instead of 32 byte
// stores -- wave store = 4x128B fully-coalesced segments.
__global__ __launch_bounds__(256) void k_node(const float* __restrict__ bl, int wbase) {
    const int tid = threadIdx.x;
    const int n0 = blockIdx.x * 64;
    const int wstart = blockIdx.y * 3;              // 0,3,6,9
    const int wend = (wstart + 3 < 11) ? wstart + 3 : 11;
    const int l = tid & 63, w = tid >> 6;
    const int mrow = l & 15, quad = l >> 4;
    const u16* xrow = g_x + (size_t)(n0 + w * 16 + mrow) * D;

    s8v a[4];
#pragma unroll
    for (int s = 0; s < 4; ++s) a[s] = *(const s8v*)&xrow[s * 32 + quad * 8];

    for (int wsel = wstart; wsel < wend; ++wsel) {
        const u16* BF = g_WnF + (size_t)(wbase + wsel) * 2048 * 8;
        f4v acc[8];
#pragma unroll
        for (int nt = 0; nt < 8; ++nt) acc[nt] = (f4v){0.f, 0.f, 0.f, 0.f};
#pragma unroll
        for (int s = 0; s < 4; ++s) {
#pragma unroll
            for (int nt = 0; nt < 8; ++nt) {
                s8v b = *(const s8v*)&BF[(size_t)((s * 8 + nt) * 64 + l) * 8];
                acc[nt] = __builtin_amdgcn_mfma_f32_16x16x32_bf16(a[s], b, acc[nt], 0, 0, 0);
            }
        }

        if (wsel == 0) {
#pragma unroll
            for (int nt = 0; nt < 8; ++nt) {
                int col = nt * 16 + mrow;
                float bias = bl[col];
                float v[4];
#pragma unroll
                for (int r = 0; r < 4; ++r) v[r] = acc[nt][r] + bias;
#pragma unroll
                for (int r = 0; r < 4; ++r) {
                    int row = n0 + w * 16 + quad * 4 + r;
                    g_xl[(size_t)row * D + col] = rnd16(v[r]);
                }
#pragma unroll
                for (int r = 0; r < 4; r += 2) {
                    u32 pk = __builtin_amdgcn_cvt_pk_fp8_f32(v[r], v[r + 1], 0, false);
                    int row = n0 + w * 16 + quad * 4 + r;
                    g_xl8[(size_t)row * D + col] = (u8)(pk & 0xffu);
                    g_xl8[(size_t)(row + 1) * D + col] = (u8)((pk >> 8) & 0xffu);
                }
            }
        } else {
            u8* out8 = (wsel <= R) ? g_P8 + (size_t)(wsel - 1) * NN * D
                                   : g_Q8 + (size_t)(wsel - 1 - R) * NN * D;
#pragma unroll
            for (int r = 0; r < 4; ++r) {
                // permuted row: byte p = 8*mrow + nt holds col 16*nt + mrow
                u32 w01 = __builtin_amdgcn_cvt_pk_fp8_f32(acc[0][r], acc[1][r], 0, false);
                u32 w23 = __builtin_amdgcn_cvt_pk_fp8_f32(acc[2][r], acc[3][r], 0, false);
                u32 w45 = __builtin_amdgcn_cvt_pk_fp8_f32(acc[4][r], acc[5][r], 0, false);
                u32 w67 = __builtin_amdgcn_cvt_pk_fp8_f32(acc[6][r], acc[7][r], 0, false);
                uint2 pk;
                pk.x = __builtin_amdgcn_perm(w23, w01, 0x05040100u);  // nt0..nt3
                pk.y = __builtin_amdgcn_perm(w67, w45, 0x05040100u);  // nt4..nt7
                int row = n0 + w * 16 + quad * 4 + r;
                *(uint2*)&out8[(size_t)row * D + mrow * 8] = pk;
            }
        }
    }
}

// ---- fused edge kernel: 1 tile/wave (r3/r6 shape -- verified optimum) ----
// block = 64 CSR positions (4 waves x 16 edges); grid NE/64
// Unchanged by R10: reads the same byte positions of P8/Q8 (now permuted
// data) and contracts against the matching permuted We B-frags.
// Lessons held: VGPR <= 64 (r5: ILP-for-TLP regressed); no re-partitioning
// (r7: latency floor, partition overhead loses).
__global__ __launch_bounds__(256) void k_edge(const float* __restrict__ att, int wbase) {
    const int tid = threadIdx.x;
    const int e0 = blockIdx.x * 64;
    const int l = tid & 63, w = tid >> 6;
    const int mrow = l & 15, quad = l >> 4;
    const int myrow = w * 16 + mrow;
    const u16* BF = g_WnF + (size_t)(wbase + 11) * 2048 * 8;

    const int se = g_se[e0 + myrow];
    const int de = g_de[e0 + myrow];
    const int re = g_re[e0 + myrow];

    // fp8 identity B-frags (e4m3 1.0 = 0x38), one byte set per contributing lane.
    const int pos8 = (mrow & 7) * 8;
    const i64 bev8 = (quad == (mrow >> 3))     ? (i64)(0x38LL << pos8) : 0LL;
    const i64 bod8 = (quad == 2 + (mrow >> 3)) ? (i64)(0x38LL << pos8) : 0LL;

    const u8* Prow = g_P8 + ((size_t)re * NN + se) * D;
    const u8* Qrow = g_Q8 + ((size_t)re * NN + de) * D;
    const u8* Xs = g_xl8 + (size_t)se * D;
    const u8* Xd = g_xl8 + (size_t)de * D;
    union { u32 u[4]; s8v v; } af[4];
    uint2 su[4], du[4];
#pragma unroll
    for (int s = 0; s < 4; ++s) {
        int c0 = s * 32 + quad * 8;
        uint2 pu = *(const uint2*)&Prow[c0];
        uint2 qu = *(const uint2*)&Qrow[c0];
        su[s] = *(const uint2*)&Xs[c0];
        du[s] = *(const uint2*)&Xd[c0];
        f2v pq0 = __builtin_amdgcn_cvt_pk_f32_fp8(pu.x, false) + __builtin_amdgcn_cvt_pk_f32_fp8(qu.x, false);
        f2v pq1 = __builtin_amdgcn_cvt_pk_f32_fp8(pu.x, true)  + __builtin_amdgcn_cvt_pk_f32_fp8(qu.x, true);
        f2v pq2 = __builtin_amdgcn_cvt_pk_f32_fp8(pu.y, false) + __builtin_amdgcn_cvt_pk_f32_fp8(qu.y, false);
        f2v pq3 = __builtin_amdgcn_cvt_pk_f32_fp8(pu.y, true)  + __builtin_amdgcn_cvt_pk_f32_fp8(qu.y, true);
        f2v g0 = gelu_pk(pq0), g1 = gelu_pk(pq1), g2 = gelu_pk(pq2), g3 = gelu_pk(pq3);
        af[s].u[0] = pack2r(g0.x, g0.y);
        af[s].u[1] = pack2r(g1.x, g1.y);
        af[s].u[2] = pack2r(g2.x, g2.y);
        af[s].u[3] = pack2r(g3.x, g3.y);
    }

    f4v acc[8];
#pragma unroll
    for (int nt = 0; nt < 8; ++nt) acc[nt] = (f4v){0.f, 0.f, 0.f, 0.f};
#pragma unroll
    for (int s = 0; s < 4; ++s) {
#pragma unroll
        for (int nt = 0; nt < 8; ++nt) {
            s8v b = *(const s8v*)&BF[(size_t)((s * 8 + nt) * 64 + l) * 8];
            acc[nt] = __builtin_amdgcn_mfma_f32_16x16x32_bf16(af[s].v, b, acc[nt], 0, 0, 0);
        }
        const i64 as = (i64)(((unsigned long long)su[s].y << 32) | su[s].x);
        const i64 ad = (i64)(((unsigned long long)du[s].y << 32) | du[s].x);
        acc[2 * s]     = __builtin_amdgcn_mfma_f32_16x16x32_fp8_fp8(as, bev8, acc[2 * s], 0, 0, 0);
        acc[2 * s]     = __builtin_amdgcn_mfma_f32_16x16x32_fp8_fp8(ad, bev8, acc[2 * s], 0, 0, 0);
        acc[2 * s + 1] = __builtin_amdgcn_mfma_f32_16x16x32_fp8_fp8(as, bod8, acc[2 * s + 1], 0, 0, 0);
        acc[2 * s + 1] = __builtin_amdgcn_mfma_f32_16x16x32_fp8_fp8(ad, bod8, acc[2 * s + 1], 0, 0, 0);
    }

    // epilogue in C-layout: edge = w*16 + quad*4 + r, col = nt*16 + mrow
    float hsum[4][4];
#pragma unroll
    for (int r = 0; r < 4; ++r)
#pragma unroll
        for (int h = 0; h < 4; ++h) hsum[r][h] = 0.f;
#pragma unroll
    for (int nt = 0; nt < 8; ++nt) {
        int col = nt * 16 + mrow;
        float av = att[col];
        int h = nt >> 1;
#pragma unroll
        for (int r = 0; r < 4; ++r) {
            float m = acc[nt][r];
            float lr = fmaxf(m, 0.2f * m);   // leaky_relu, slope 0.2
            hsum[r][h] = fmaf(lr, av, hsum[r][h]);
        }
    }
#pragma unroll
    for (int r = 0; r < 4; ++r)
#pragma unroll
        for (int h = 0; h < 4; ++h) hsum[r][h] = rsum16(hsum[r][h]);
    if ((mrow & 3) == 0) {   // store exp(logit) directly
        int r = mrow >> 2;
        float4 v = make_float4(__expf(fminf(hsum[r][0], 80.f)),
                               __expf(fminf(hsum[r][1], 80.f)),
                               __expf(fminf(hsum[r][2], 80.f)),
                               __expf(fminf(hsum[r][3], 80.f)));
        *(float4*)&g_araw[(size_t)(e0 + w * 16 + quad * 4 + r) * H] = v;
    }
}

// ---- fused gather: single-pass aggregate over pre-computed exp(logit) ----
// one wave per dst; block 256 = 4 dsts; grid NN/4; 8-deep unroll (r6)
__global__ __launch_bounds__(256) void k_gath(const float* __restrict__ bias,
                                              int do_gelu) {
    const int lane = threadIdx.x & 63;
    const int d = blockIdx.x * 4 + (threadIdx.x >> 6);
    const int off = g_off[d];
    const int deg = g_off[d + 1] - off;
    const int h = lane >> 4;        // head for cols 2*lane, 2*lane+1

    const int* __restrict__ srcs = g_se + off;
    const float* __restrict__ ar = g_araw + (size_t)off * H + h;
    float a0 = 0.f, a1 = 0.f, dn = 0.f;
    int p = 0;
    for (; p + 8 <= deg; p += 8) {
        int ss[8];
#pragma unroll
        for (int j = 0; j < 8; ++j) ss[j] = srcs[p + j];
        u32 ww[8];
#pragma unroll
        for (int j = 0; j < 8; ++j) ww[j] = *(const u32*)&g_xl[(size_t)ss[j] * D + lane * 2];
        float cc[8];
#pragma unroll
        for (int j = 0; j < 8; ++j) cc[j] = ar[(p + j) * H];
#pragma unroll
        for (int j = 0; j < 8; ++j) {
            dn += cc[j];
            a0 = fmaf(bflo(ww[j]), cc[j], a0);
            a1 = fmaf(bfhi(ww[j]), cc[j], a1);
        }
    }
    for (; p + 4 <= deg; p += 4) {
        int s0 = srcs[p], s1 = srcs[p + 1], s2 = srcs[p + 2], s3 = srcs[p + 3];
        u32 w0 = *(const u32*)&g_xl[(size_t)s0 * D + lane * 2];
        u32 w1 = *(const u32*)&g_xl[(size_t)s1 * D + lane * 2];
        u32 w2 = *(const u32*)&g_xl[(size_t)s2 * D + lane * 2];
        u32 w3 = *(const u32*)&g_xl[(size_t)s3 * D + lane * 2];
        float c0 = ar[(p + 0) * H];
        float c1 = ar[(p + 1) * H];
        float c2 = ar[(p + 2) * H];
        float c3 = ar[(p + 3) * H];
        dn += (c0 + c1) + (c2 + c3);
        a0 = fmaf(bflo(w0), c0, a0); a1 = fmaf(bfhi(w0), c0, a1);
        a0 = fmaf(bflo(w1), c1, a0); a1 = fmaf(bfhi(w1), c1, a1);
        a0 = fmaf(bflo(w2), c2, a0); a1 = fmaf(bfhi(w2), c2, a1);
        a0 = fmaf(bflo(w3), c3, a0); a1 = fmaf(bfhi(w3), c3, a1);
    }
    for (; p < deg; ++p) {
        int s = srcs[p];
        u32 w = *(const u32*)&g_xl[(size_t)s * D + lane * 2];
        float cf = ar[p * H];
        dn += cf;
        a0 = fmaf(bflo(w), cf, a0);
        a1 = fmaf(bfhi(w), cf, a1);
    }
    const float inv = __builtin_amdgcn_rcpf(dn + 1e-16f);
    float v0 = a0 * inv + bias[lane * 2];
    float v1 = a1 * inv + bias[lane * 2 + 1];
    if (do_gelu) { v0 = gelu_f(v0); v1 = gelu_f(v1); }
    ((u32*)g_x)[(size_t)d * (D / 2) + lane] = pack2r(v0, v1);
}

// ---- output head (MFMA, LDS-free): y = x[:BS]@out_w + out_b; LayerNorm ----
__global__ __launch_bounds__(256) void k_head(const float* __restrict__ ob,
                                              const float* __restrict__ g,
                                              const float* __restrict__ b,
                                              float* __restrict__ out) {
    const int tid = threadIdx.x;
    const int r0 = blockIdx.x * 64;
    const int l = tid & 63, w = tid >> 6;
    const int mrow = l & 15, quad = l >> 4;
    const u16* xrow = g_x + (size_t)(r0 + w * 16 + mrow) * D;
    const u16* BF = g_WnF + (size_t)12 * 2048 * 8;

    f4v acc[8];
#pragma unroll
    for (int nt = 0; nt < 8; ++nt) acc[nt] = (f4v){0.f, 0.f, 0.f, 0.f};
#pragma unroll
    for (int s = 0; s < 4; ++s) {
        s8v a = *(const s8v*)&xrow[s * 32 + quad * 8];
#pragma unroll
        for (int nt = 0; nt < 8; ++nt) {
            s8v bb = *(const s8v*)&BF[(size_t)((s * 8 + nt) * 64 + l) * 8];
            acc[nt] = __builtin_amdgcn_mfma_f32_16x16x32_bf16(a, bb, acc[nt], 0, 0, 0);
        }
    }

    float sum[4] = {0.f, 0.f, 0.f, 0.f};
#pragma unroll
    for (int nt = 0; nt < 8; ++nt) {
        float obv = ob[nt * 16 + mrow];
#pragma unroll
        for (int r = 0; r < 4; ++r) {
            acc[nt][r] += obv;
            sum[r] += acc[nt][r];
        }
    }
    float mu[4];
#pragma unroll
    for (int r = 0; r < 4; ++r) mu[r] = rsum16(sum[r]) * (1.f / D);
    float sq[4] = {0.f, 0.f, 0.f, 0.f};
#pragma unroll
    for (int nt = 0; nt < 8; ++nt)
#pragma unroll
        for (int r = 0; r < 4; ++r) {
            float dv = acc[nt][r] - mu[r];
            sq[r] += dv * dv;
        }
    float rs[4];
#pragma unroll
    for (int r = 0; r < 4; ++r) rs[r] = rsqrtf(rsum16(sq[r]) * (1.f / D) + 1e-12f);
#pragma unroll
    for (int nt = 0; nt < 8; ++nt) {
        int col = nt * 16 + mrow;
        float gv = g[col], bv = b[col];
#pragma unroll
        for (int r = 0; r < 4; ++r) {
            int row = r0 + w * 16 + quad * 4 + r;
            out[(size_t)row * D + col] = (acc[nt][r] - mu[r]) * rs[r] * gv + bv;
        }
    }
}

extern "C" void kernel_launch(void* const* d_in, const int* in_sizes, int n_in,
                              void* d_out, int out_size, void* d_ws, size_t ws_size,
                              hipStream_t stream) {
    (void)in_sizes; (void)n_in; (void)out_size; (void)d_ws; (void)ws_size;
    const float* embs = (const float*)d_in[0];
    const int*   ei   = (const int*)d_in[1];
    const int*   et   = (const int*)d_in[2];
    const float* rel  = (const float*)d_in[3];
    const float* wl[2]   = { (const float*)d_in[4],  (const float*)d_in[9]  };
    const float* bl[2]   = { (const float*)d_in[5],  (const float*)d_in[10] };
    const float* we[2]   = { (const float*)d_in[6],  (const float*)d_in[11] };
    const float* attw[2] = { (const float*)d_in[7],  (const float*)d_in[12] };
    const float* bs[2]   = { (const float*)d_in[8],  (const float*)d_in[13] };
    const float* ow  = (const float*)d_in[14];
    const float* ob  = (const float*)d_in[15];
    const float* lng = (const float*)d_in[16];
    const float* lnb = (const float*)d_in[17];
    float* out = (float*)d_out;

    // fused: embs->bf16 convert + CSR counter zeroing (one launch)
    k_init<<<NN * D / 512 + NN / 256, 256, 0, stream>>>(embs);

    // weight prep for BOTH layers up front
    for (int l = 0; l < 2; ++l) {
        const float* Rm = rel + (size_t)l * R * 2 * D * D;
        k_prep<<<dim3(2048 / 256, 13), 256, 0, stream>>>(wl[l], Rm, we[l], ow, l * 13);
    }

    // CSR by dst (edge list shared by both layers)
    k_count<<<NE / 256, 256, 0, stream>>>(ei);
    k_scan<<<1, 1024, 0, stream>>>();
    k_scatter<<<NE / 256, 256, 0, stream>>>(ei, et);

    for (int l = 0; l < 2; ++l) {
        k_node<<<dim3(NN / 64, 4), 256, 0, stream>>>(bl[l], l * 13);
        k_edge<<<NE / 64, 256, 0, stream>>>(attw[l], l * 13);
        k_gath<<<NN / 4, 256, 0, stream>>>(bs[l], l == 0 ? 1 : 0);
    }

    k_head<<<BS / 64, 256, 0, stream>>>(ob, lng, lnb, out);
}